// Round 8
// baseline (358.761 us; speedup 1.0000x reference)
//
#include <hip/hip_runtime.h>

#define B_ 8
#define L_ 512
#define D_ 1024
#define N_ 8192
#define GD_ 64
#define K_ 256
#define CD_ 24  // candidate-list depth

// col-quad swizzle for the x LDS tile in gproj
#define XQ(q) ((q) ^ (((q) >> 4) & 7))

// ---------------- Kernel 0: transpose W (64,1024) -> Wt (1024,64) ----------------
__global__ __launch_bounds__(256) void wt_kernel(const float* __restrict__ W,
                                                 float* __restrict__ Wt) {
  int idx = blockIdx.x * 256 + threadIdx.x;  // 65536 elems
  int d = idx >> 6, g = idx & 63;
  Wt[idx] = W[(size_t)g * D_ + d];
}

// ------- Kernel 1: g = x @ W^T, gn = ||g||, gu = g/max(gn,1e-12) -------
// 256 blocks x 256 thr; block = 16 tokens. thread = (dq = 4 dims, kg = 64 contig k).
// W slice in REGISTERS, x staged once in swizzled LDS; kg-partials reduced ascending.
__global__ __launch_bounds__(256) void gproj_kernel(const float* __restrict__ x,
                                                    const float* __restrict__ Wt,
                                                    float* __restrict__ gu,
                                                    float* __restrict__ gn) {
  __shared__ __align__(16) float xs[16 * 1024];    // 64 KB
  __shared__ __align__(16) float red[16][16][64];  // 64 KB [kg][tok][dim]
  int blk = blockIdx.x;
  int b = blk >> 5;
  int t0 = (blk & 31) * 16;
  int tid = threadIdx.x;
  const float* xb = x + ((size_t)b * L_ + t0) * D_;
  for (int r = 0; r < 16; ++r) {
    int idx = r * 256 + tid;
    int tok = idx >> 8, q = idx & 255;
    float4 v = *(const float4*)(xb + (size_t)tok * D_ + q * 4);
    *(float4*)&xs[tok * 1024 + XQ(q) * 4] = v;
  }
  __syncthreads();
  int dq = tid & 15, kg = tid >> 4;
  float acc[16][4];
#pragma unroll
  for (int t = 0; t < 16; ++t)
#pragma unroll
    for (int d = 0; d < 4; ++d) acc[t][d] = 0.f;
  const float* wbase = Wt + (size_t)(kg * 64) * GD_ + dq * 4;
#pragma unroll 1
  for (int sub = 0; sub < 4; ++sub) {
    float4 wv[16];
#pragma unroll
    for (int kk = 0; kk < 16; ++kk)
      wv[kk] = *(const float4*)(wbase + (size_t)(sub * 16 + kk) * GD_);
#pragma unroll
    for (int tok = 0; tok < 16; ++tok) {
      float4 xv[4];
#pragma unroll
      for (int kq = 0; kq < 4; ++kq) {
        int q = kg * 16 + sub * 4 + kq;
        xv[kq] = *(const float4*)&xs[tok * 1024 + XQ(q) * 4];
      }
#pragma unroll
      for (int kq = 0; kq < 4; ++kq) {
        float xc[4] = {xv[kq].x, xv[kq].y, xv[kq].z, xv[kq].w};
#pragma unroll
        for (int c = 0; c < 4; ++c) {
          float4 w = wv[kq * 4 + c];
          acc[tok][0] += xc[c] * w.x;
          acc[tok][1] += xc[c] * w.y;
          acc[tok][2] += xc[c] * w.z;
          acc[tok][3] += xc[c] * w.w;
        }
      }
    }
  }
#pragma unroll
  for (int tok = 0; tok < 16; ++tok) {
    float4 p;
    p.x = acc[tok][0]; p.y = acc[tok][1]; p.z = acc[tok][2]; p.w = acc[tok][3];
    *(float4*)&red[kg][tok][dq * 4] = p;
  }
  __syncthreads();
  int tok = tid >> 4, dqo = tid & 15;
  float g[4] = {0.f, 0.f, 0.f, 0.f};
#pragma unroll
  for (int k = 0; k < 16; ++k) {
    float4 p = *(const float4*)&red[k][tok][dqo * 4];
    g[0] += p.x; g[1] += p.y; g[2] += p.z; g[3] += p.w;
  }
  double ss = 0.0;
#pragma unroll
  for (int d = 0; d < 4; ++d) ss += (double)g[d] * (double)g[d];
#pragma unroll
  for (int off = 1; off < 16; off <<= 1) ss += __shfl_xor(ss, off);
  float gnv = (float)sqrt(ss);
  float dn = fmaxf(gnv, 1e-12f);
  int t = t0 + tok;
  if (dqo == 0) gn[(size_t)b * L_ + t] = gnv;
  float4 o;
  o.x = g[0] / dn; o.y = g[1] / dn; o.z = g[2] / dn; o.w = g[3] / dn;
  *(float4*)(gu + ((size_t)b * L_ + t) * GD_ + dqo * 4) = o;
}

// ------- Kernel 2: fused sim band + per-token sorted top-CD_ candidates -------
// grid (32 bands, 8 batches) x 256 thr; band = 16 rows. Phase 1: sim row-band into
// LDS (fp64 accum) + global sim. Phase 2: top-CD_ keys per row from LDS.
__global__ __launch_bounds__(256) void sim_topk_kernel(const float* __restrict__ gu,
                                                       float* __restrict__ simo,
                                                       unsigned long long* __restrict__ cand) {
  __shared__ __align__(16) float simL[16][512];  // 32 KB
  __shared__ __align__(16) float BsT[64][68];    // 17 KB
  int b = blockIdx.y;
  int i0 = blockIdx.x * 16;
  const float* gb = gu + (size_t)b * L_ * GD_;
  int tid = threadIdx.x;
  int r = tid >> 4, c4 = (tid & 15) * 4;
  float af[GD_];
  const float4* arow = (const float4*)(gb + (size_t)(i0 + r) * GD_);
#pragma unroll
  for (int q = 0; q < 16; ++q) *(float4*)&af[q * 4] = arow[q];
  float* sgl = simo + (size_t)b * L_ * L_;
#pragma unroll 1
  for (int jt = 0; jt < 8; ++jt) {
    int j0 = jt * 64;
    for (int f = tid; f < 64 * GD_; f += 256) {
      int br = f >> 6, k = f & 63;
      BsT[k][br] = gb[(size_t)(j0 + br) * GD_ + k];
    }
    __syncthreads();
    double a0 = 0, a1 = 0, a2 = 0, a3 = 0;
#pragma unroll
    for (int k = 0; k < GD_; ++k) {
      double a = (double)af[k];
      float4 bv = *(const float4*)&BsT[k][c4];
      a0 += a * (double)bv.x;
      a1 += a * (double)bv.y;
      a2 += a * (double)bv.z;
      a3 += a * (double)bv.w;
    }
    float4 o;
    o.x = (float)a0; o.y = (float)a1; o.z = (float)a2; o.w = (float)a3;
    *(float4*)&simL[r][j0 + c4] = o;
    *(float4*)(sgl + (size_t)(i0 + r) * L_ + (j0 + c4)) = o;
    __syncthreads();
  }
  // phase 2: per-row top-CD_ (1 row per wave at a time)
  int wave = tid >> 6, lane = tid & 63;
  for (int rr = wave; rr < 16; rr += 4) {
    int a = i0 + rr;
    int c0 = lane * 8;
    float vv[8];
#pragma unroll
    for (int s = 0; s < 8; ++s) vv[s] = simL[rr][c0 + s];
    unsigned long long k[8];
#pragma unroll
    for (int s = 0; s < 8; ++s) {
      int bb = c0 + s;
      if (bb == a) {
        k[s] = 0;
      } else {
        unsigned u = __float_as_uint(vv[s]);
        u = (u & 0x80000000u) ? ~u : (u | 0x80000000u);
        int i = a < bb ? a : bb, j = a < bb ? bb : a;
        k[s] = ((unsigned long long)u << 18) |
               (unsigned long long)(0x3FFFFu - (((unsigned)i << 9) | (unsigned)j));
      }
    }
    unsigned long long* out = cand + ((size_t)b * L_ + a) * CD_;
#pragma unroll 1
    for (int pass = 0; pass < CD_; ++pass) {
      unsigned long long m = k[0];
#pragma unroll
      for (int s = 1; s < 8; ++s) m = k[s] > m ? k[s] : m;
#pragma unroll
      for (int off = 32; off; off >>= 1) {
        unsigned long long o = __shfl_xor(m, off);
        if (o > m) m = o;
      }
#pragma unroll
      for (int s = 0; s < 8; ++s)
        if (k[s] == m) k[s] = 0;
      if (lane == 0) out[pass] = m;
    }
  }
}

// ------- Kernel 3: mutual-best matching; depth-24 cand lists in LDS; 3 barriers/round
__global__ __launch_bounds__(512) void match_kernel(const float* __restrict__ sim,
                                                    const unsigned long long* __restrict__ cand,
                                                    int* __restrict__ keepI,
                                                    int* __restrict__ keepJ) {
  int b = blockIdx.x;
  const float* S = sim + (size_t)b * L_ * L_;
  const unsigned long long* C = cand + (size_t)b * L_ * CD_;
  __shared__ unsigned long long candL[L_][CD_];  // 96 KB
  __shared__ unsigned long long bestkey[L_];
  __shared__ short partner[L_];
  __shared__ short liveA[L_], liveB[L_], rescanQ[L_];
  __shared__ unsigned char liveF[L_], needs[L_], head[L_];
  __shared__ int cnt[2], nQ[2];
  int tid = threadIdx.x;
  int wave = tid >> 6, lane = tid & 63;
  for (int f = tid; f < L_ * (CD_ / 2); f += 512)
    ((ulonglong2*)candL)[f] = ((const ulonglong2*)C)[f];
  if (tid < L_) {
    partner[tid] = -1;
    liveF[tid] = 1;
    needs[tid] = 1;
    head[tid] = 0;
    liveA[tid] = (short)tid;
    bestkey[tid] = 0ull;
  }
  if (tid == 0) {
    cnt[0] = L_; cnt[1] = 0;
    nQ[0] = 0; nQ[1] = 0;
  }
  __syncthreads();
  for (int round = 0; round < 300; ++round) {
    int par = round & 1;
    int nLive = cnt[par];
    if (nLive == 0) break;
    short* cur = par ? liveB : liveA;
    short* nxt = par ? liveA : liveB;
    // A: candidate-list pops (thread-per-token); reset next-round counters
    if (tid == 0) {
      cnt[par ^ 1] = 0;
      nQ[par ^ 1] = 0;
    }
    for (int idx = tid; idx < nLive; idx += 512) {
      int a = cur[idx];
      if (needs[a]) {
        int h = head[a];
        unsigned long long bk = 0ull;
        while (h < CD_) {
          unsigned long long key = candL[a][h];
          if (key) {
            unsigned pk = 0x3FFFFu - (unsigned)(key & 0x3FFFFull);
            int i = (int)(pk >> 9), j = (int)(pk & 511u);
            int p = (i == a) ? j : i;
            if (liveF[p]) { bk = key; break; }
          }
          ++h;
        }
        head[a] = (unsigned char)h;
        if (bk) {
          bestkey[a] = bk;
          needs[a] = 0;
        } else {
          int q = atomicAdd(&nQ[par], 1);
          rescanQ[q] = (short)a;
        }
      }
    }
    __syncthreads();
    // A2 (rare with depth 24): full rescan for exhausted lists
    int nq = nQ[par];
    if (nq > 0) {
      for (int q = wave; q < nq; q += 8) {
        int a = rescanQ[q];
        unsigned long long mk = 0ull;
        for (int kk = lane; kk < nLive; kk += 64) {
          int bb = cur[kk];
          if (bb != a) {
            float sv = S[(size_t)a * L_ + bb];
            unsigned u = __float_as_uint(sv);
            u = (u & 0x80000000u) ? ~u : (u | 0x80000000u);
            int i = a < bb ? a : bb, j = a < bb ? bb : a;
            unsigned long long key =
                ((unsigned long long)u << 18) |
                (unsigned long long)(0x3FFFFu - (((unsigned)i << 9) | (unsigned)j));
            if (key > mk) mk = key;
          }
        }
#pragma unroll
        for (int off = 32; off; off >>= 1) {
          unsigned long long o = __shfl_xor(mk, off);
          if (o > mk) mk = o;
        }
        if (lane == 0) {
          bestkey[a] = mk;
          needs[a] = 0;
        }
      }
      __syncthreads();
    }
    // B: mutual-best match
    for (int idx = tid; idx < nLive; idx += 512) {
      int a = cur[idx];
      unsigned pk = 0x3FFFFu - (unsigned)(bestkey[a] & 0x3FFFFull);
      int i = (int)(pk >> 9), j = (int)(pk & 511u);
      int p = (i == a) ? j : i;
      unsigned pk2 = 0x3FFFFu - (unsigned)(bestkey[p] & 0x3FFFFull);
      int i2 = (int)(pk2 >> 9), j2 = (int)(pk2 & 511u);
      int p2 = (i2 == p) ? j2 : i2;
      if (p2 == a) {
        partner[a] = (short)p;
        liveF[a] = 0;
      }
    }
    __syncthreads();
    // C: compact live list into nxt + mark tokens whose best died
    for (int idx = tid; idx < nLive; idx += 512) {
      int a = cur[idx];
      if (liveF[a]) {
        unsigned pk = 0x3FFFFu - (unsigned)(bestkey[a] & 0x3FFFFull);
        int i = (int)(pk >> 9), j = (int)(pk & 511u);
        int p = (i == a) ? j : i;
        if (!liveF[p]) needs[a] = 1;
        int pos = atomicAdd(&cnt[par ^ 1], 1);
        nxt[pos] = (short)a;
      }
    }
    __syncthreads();
  }
  // keep list: kept token = smaller index of each pair, ascending order
  if (wave == 0) {
    int base = 0;
    for (int c = 0; c < 8; ++c) {
      int a = c * 64 + lane;
      bool kept = partner[a] > a;
      unsigned long long m = __ballot(kept);
      int pos = base + (int)__popcll(m & ((1ull << lane) - 1ull));
      if (kept) {
        keepI[b * K_ + pos] = a;
        keepJ[b * K_ + pos] = partner[a];
      }
      base += (int)__popcll(m);
    }
  }
}

// ------- Kernel 4: fused merge; 4096 blocks (2 per output row) -------
__global__ __launch_bounds__(256) void merge_kernel(const float* __restrict__ x,
                                                    const float* __restrict__ s,
                                                    const float* __restrict__ gn,
                                                    const int* __restrict__ keepI,
                                                    const int* __restrict__ keepJ,
                                                    float* __restrict__ xm,
                                                    float* __restrict__ sm) {
  int blk = blockIdx.x;  // 4096
  int row = blk >> 1, half = blk & 1;
  int b = row >> 8;
  int i = keepI[row], j = keepJ[row];
  int t = threadIdx.x;
  if (half == 0) {
    float wi = gn[(size_t)b * L_ + i], wj = gn[(size_t)b * L_ + j];
    float tot = wi + wj + 1e-8f;
    const float4* xi = (const float4*)(x + ((size_t)b * L_ + i) * D_);
    const float4* xj = (const float4*)(x + ((size_t)b * L_ + j) * D_);
    float4* o = (float4*)(xm + (size_t)row * D_);
    float4 a = xi[t], c = xj[t];
    float4 r;
    r.x = (wi * a.x + wj * c.x) / tot;
    r.y = (wi * a.y + wj * c.y) / tot;
    r.z = (wi * a.z + wj * c.z) / tot;
    r.w = (wi * a.w + wj * c.w) / tot;
    o[t] = r;
  }
  {
    size_t off = (size_t)half * (N_ / 2);
    const float4* si = (const float4*)(s + ((size_t)b * L_ + i) * N_ + off);
    const float4* sj = (const float4*)(s + ((size_t)b * L_ + j) * N_ + off);
    float4* o = (float4*)(sm + (size_t)row * N_ + off);
    for (int tt = t; tt < N_ / 8; tt += 256) {
      float4 a = si[tt], c = sj[tt];
      float4 r;
      r.x = a.x + c.x;
      r.y = a.y + c.y;
      r.z = a.z + c.z;
      r.w = a.w + c.w;
      o[tt] = r;
    }
  }
}

extern "C" void kernel_launch(void* const* d_in, const int* in_sizes, int n_in,
                              void* d_out, int out_size, void* d_ws, size_t ws_size,
                              hipStream_t stream) {
  (void)in_sizes; (void)n_in; (void)out_size; (void)ws_size;
  const float* x = (const float*)d_in[0];
  const float* src = (const float*)d_in[1];
  const float* W = (const float*)d_in[2];

  float* ws = (float*)d_ws;
  float* Wt = ws;                                   // 65536
  float* gu = Wt + 65536;                           // 262144
  float* gn = gu + (size_t)B_ * L_ * GD_;           // 4096
  float* sim = gn + (size_t)B_ * L_;                // 2097152
  int* keepI = (int*)(sim + (size_t)B_ * L_ * L_);  // 2048
  int* keepJ = keepI + B_ * K_;                     // 2048
  unsigned long long* cand = (unsigned long long*)(keepJ + B_ * K_);  // 8*512*24 u64

  float* xm = (float*)d_out;
  float* sm = xm + (size_t)B_ * K_ * D_;

  wt_kernel<<<256, 256, 0, stream>>>(W, Wt);
  gproj_kernel<<<256, 256, 0, stream>>>(x, Wt, gu, gn);
  sim_topk_kernel<<<dim3(32, 8), 256, 0, stream>>>(gu, sim, cand);
  match_kernel<<<B_, 512, 0, stream>>>(sim, cand, keepI, keepJ);
  merge_kernel<<<B_ * K_ * 2, 256, 0, stream>>>(x, src, gn, keepI, keepJ, xm, sm);
}

// Round 9
// 307.714 us; speedup vs baseline: 1.1659x; 1.1659x over previous
//
#include <hip/hip_runtime.h>

#define B_ 8
#define L_ 512
#define D_ 1024
#define N_ 8192
#define GD_ 64
#define K_ 256
#define CD_ 16  // candidate-list depth

// col-quad swizzle for the x LDS tile in gproj
#define XQ(q) ((q) ^ (((q) >> 4) & 7))

// ---------------- Kernel 0: transpose W (64,1024) -> Wt (1024,64) ----------------
__global__ __launch_bounds__(256) void wt_kernel(const float* __restrict__ W,
                                                 float* __restrict__ Wt) {
  int idx = blockIdx.x * 256 + threadIdx.x;  // 65536 elems
  int d = idx >> 6, g = idx & 63;
  Wt[idx] = W[(size_t)g * D_ + d];
}

// ------- Kernel 1: g = x @ W^T, gn = ||g||, gu = g/max(gn,1e-12) -------
// 256 blocks x 256 thr; block = 16 tokens. thread = (dq = 4 dims, kg = 64 contig k).
// W slice in REGISTERS, x staged once in swizzled LDS; kg-partials reduced ascending.
__global__ __launch_bounds__(256) void gproj_kernel(const float* __restrict__ x,
                                                    const float* __restrict__ Wt,
                                                    float* __restrict__ gu,
                                                    float* __restrict__ gn) {
  __shared__ __align__(16) float xs[16 * 1024];    // 64 KB
  __shared__ __align__(16) float red[16][16][64];  // 64 KB [kg][tok][dim]
  int blk = blockIdx.x;
  int b = blk >> 5;
  int t0 = (blk & 31) * 16;
  int tid = threadIdx.x;
  const float* xb = x + ((size_t)b * L_ + t0) * D_;
  for (int r = 0; r < 16; ++r) {
    int idx = r * 256 + tid;
    int tok = idx >> 8, q = idx & 255;
    float4 v = *(const float4*)(xb + (size_t)tok * D_ + q * 4);
    *(float4*)&xs[tok * 1024 + XQ(q) * 4] = v;
  }
  __syncthreads();
  int dq = tid & 15, kg = tid >> 4;
  float acc[16][4];
#pragma unroll
  for (int t = 0; t < 16; ++t)
#pragma unroll
    for (int d = 0; d < 4; ++d) acc[t][d] = 0.f;
  const float* wbase = Wt + (size_t)(kg * 64) * GD_ + dq * 4;
#pragma unroll 1
  for (int sub = 0; sub < 4; ++sub) {
    float4 wv[16];
#pragma unroll
    for (int kk = 0; kk < 16; ++kk)
      wv[kk] = *(const float4*)(wbase + (size_t)(sub * 16 + kk) * GD_);
#pragma unroll
    for (int tok = 0; tok < 16; ++tok) {
      float4 xv[4];
#pragma unroll
      for (int kq = 0; kq < 4; ++kq) {
        int q = kg * 16 + sub * 4 + kq;
        xv[kq] = *(const float4*)&xs[tok * 1024 + XQ(q) * 4];
      }
#pragma unroll
      for (int kq = 0; kq < 4; ++kq) {
        float xc[4] = {xv[kq].x, xv[kq].y, xv[kq].z, xv[kq].w};
#pragma unroll
        for (int c = 0; c < 4; ++c) {
          float4 w = wv[kq * 4 + c];
          acc[tok][0] += xc[c] * w.x;
          acc[tok][1] += xc[c] * w.y;
          acc[tok][2] += xc[c] * w.z;
          acc[tok][3] += xc[c] * w.w;
        }
      }
    }
  }
#pragma unroll
  for (int tok = 0; tok < 16; ++tok) {
    float4 p;
    p.x = acc[tok][0]; p.y = acc[tok][1]; p.z = acc[tok][2]; p.w = acc[tok][3];
    *(float4*)&red[kg][tok][dq * 4] = p;
  }
  __syncthreads();
  int tok = tid >> 4, dqo = tid & 15;
  float g[4] = {0.f, 0.f, 0.f, 0.f};
#pragma unroll
  for (int k = 0; k < 16; ++k) {
    float4 p = *(const float4*)&red[k][tok][dqo * 4];
    g[0] += p.x; g[1] += p.y; g[2] += p.z; g[3] += p.w;
  }
  double ss = 0.0;
#pragma unroll
  for (int d = 0; d < 4; ++d) ss += (double)g[d] * (double)g[d];
#pragma unroll
  for (int off = 1; off < 16; off <<= 1) ss += __shfl_xor(ss, off);
  float gnv = (float)sqrt(ss);
  float dn = fmaxf(gnv, 1e-12f);
  int t = t0 + tok;
  if (dqo == 0) gn[(size_t)b * L_ + t] = gnv;
  float4 o;
  o.x = g[0] / dn; o.y = g[1] / dn; o.z = g[2] / dn; o.w = g[3] / dn;
  *(float4*)(gu + ((size_t)b * L_ + t) * GD_ + dqo * 4) = o;
}

// ------- Kernel 2: full 512x512 cosine-sim matrix per batch -------
__global__ __launch_bounds__(256) void sim_kernel(const float* __restrict__ gu,
                                                  float* __restrict__ simo) {
  __shared__ __align__(16) float BsT[GD_][36];
  int b = blockIdx.z;
  int i0 = blockIdx.y * 32, j0 = blockIdx.x * 32;
  const float* gb = gu + (size_t)b * L_ * GD_;
  int tid = threadIdx.x;
  for (int f = tid; f < 32 * GD_; f += 256) {
    int r = f >> 6, k = f & 63;
    BsT[k][r] = gb[(size_t)(j0 + r) * GD_ + k];
  }
  int r = tid >> 3, c4 = (tid & 7) * 4;
  float af[GD_];
  const float4* arow = (const float4*)(gb + (size_t)(i0 + r) * GD_);
#pragma unroll
  for (int q = 0; q < 16; ++q) *(float4*)&af[q * 4] = arow[q];
  __syncthreads();
  double a0 = 0, a1 = 0, a2 = 0, a3 = 0;
#pragma unroll
  for (int k = 0; k < GD_; ++k) {
    double a = (double)af[k];
    float4 bv = *(const float4*)&BsT[k][c4];
    a0 += a * (double)bv.x;
    a1 += a * (double)bv.y;
    a2 += a * (double)bv.z;
    a3 += a * (double)bv.w;
  }
  float4 o;
  o.x = (float)a0; o.y = (float)a1; o.z = (float)a2; o.w = (float)a3;
  *(float4*)(simo + (size_t)b * L_ * L_ + (size_t)(i0 + r) * L_ + (j0 + c4)) = o;
}

// ------- Kernel 3: per-token sorted top-CD_ candidate keys -------
__global__ __launch_bounds__(256) void topk_kernel(const float* __restrict__ sim,
                                                   unsigned long long* __restrict__ cand) {
  int wid = blockIdx.x * 4 + (threadIdx.x >> 6);  // 0..4095
  int b = wid >> 9;
  int a = wid & 511;
  int lane = threadIdx.x & 63;
  const float* row = sim + ((size_t)b * L_ + a) * L_;
  int c0 = lane * 8;
  float4 v0 = *(const float4*)(row + c0);
  float4 v1 = *(const float4*)(row + c0 + 4);
  float vv[8] = {v0.x, v0.y, v0.z, v0.w, v1.x, v1.y, v1.z, v1.w};
  unsigned long long k[8];
#pragma unroll
  for (int s = 0; s < 8; ++s) {
    int bb = c0 + s;
    if (bb == a) {
      k[s] = 0;
    } else {
      unsigned u = __float_as_uint(vv[s]);
      u = (u & 0x80000000u) ? ~u : (u | 0x80000000u);
      int i = a < bb ? a : bb, j = a < bb ? bb : a;
      k[s] = ((unsigned long long)u << 18) |
             (unsigned long long)(0x3FFFFu - (((unsigned)i << 9) | (unsigned)j));
    }
  }
  unsigned long long* out = cand + ((size_t)b * L_ + a) * CD_;
#pragma unroll
  for (int pass = 0; pass < CD_; ++pass) {
    unsigned long long m = k[0];
#pragma unroll
    for (int s = 1; s < 8; ++s) m = k[s] > m ? k[s] : m;
#pragma unroll
    for (int off = 32; off; off >>= 1) {
      unsigned long long o = __shfl_xor(m, off);
      if (o > m) m = o;
    }
#pragma unroll
    for (int s = 0; s < 8; ++s)
      if (k[s] == m) k[s] = 0;
    if (lane == 0) out[pass] = m;
  }
}

// ------- Kernel 4: mutual-best matching; cand lists in LDS; 3 barriers/round -------
__global__ __launch_bounds__(512) void match_kernel(const float* __restrict__ sim,
                                                    const unsigned long long* __restrict__ cand,
                                                    int* __restrict__ keepI,
                                                    int* __restrict__ keepJ) {
  int b = blockIdx.x;
  const float* S = sim + (size_t)b * L_ * L_;
  const unsigned long long* C = cand + (size_t)b * L_ * CD_;
  __shared__ unsigned long long candL[L_][CD_];  // 64 KB
  __shared__ unsigned long long bestkey[L_];
  __shared__ short partner[L_];
  __shared__ short liveA[L_], liveB[L_], rescanQ[L_];
  __shared__ unsigned char liveF[L_], needs[L_], head[L_];
  __shared__ int cnt[2], nQ[2];
  int tid = threadIdx.x;
  int wave = tid >> 6, lane = tid & 63;
  for (int f = tid; f < L_ * (CD_ / 2); f += 512)
    ((ulonglong2*)candL)[f] = ((const ulonglong2*)C)[f];
  if (tid < L_) {
    partner[tid] = -1;
    liveF[tid] = 1;
    needs[tid] = 1;
    head[tid] = 0;
    liveA[tid] = (short)tid;
    bestkey[tid] = 0ull;
  }
  if (tid == 0) {
    cnt[0] = L_; cnt[1] = 0;
    nQ[0] = 0; nQ[1] = 0;
  }
  __syncthreads();
  for (int round = 0; round < 300; ++round) {
    int par = round & 1;
    int nLive = cnt[par];
    if (nLive == 0) break;
    short* cur = par ? liveB : liveA;
    short* nxt = par ? liveA : liveB;
    // A: candidate-list pops (thread-per-token); reset next-round counters
    if (tid == 0) {
      cnt[par ^ 1] = 0;
      nQ[par ^ 1] = 0;
    }
    for (int idx = tid; idx < nLive; idx += 512) {
      int a = cur[idx];
      if (needs[a]) {
        int h = head[a];
        unsigned long long bk = 0ull;
        while (h < CD_) {
          unsigned long long key = candL[a][h];
          if (key) {
            unsigned pk = 0x3FFFFu - (unsigned)(key & 0x3FFFFull);
            int i = (int)(pk >> 9), j = (int)(pk & 511u);
            int p = (i == a) ? j : i;
            if (liveF[p]) { bk = key; break; }
          }
          ++h;
        }
        head[a] = (unsigned char)h;
        if (bk) {
          bestkey[a] = bk;
          needs[a] = 0;
        } else {
          int q = atomicAdd(&nQ[par], 1);
          rescanQ[q] = (short)a;
        }
      }
    }
    __syncthreads();
    // A2: full rescan for exhausted lists (skipped entirely when none)
    int nq = nQ[par];
    if (nq > 0) {
      for (int q = wave; q < nq; q += 8) {
        int a = rescanQ[q];
        unsigned long long mk = 0ull;
        for (int kk = lane; kk < nLive; kk += 64) {
          int bb = cur[kk];
          if (bb != a) {
            float sv = S[(size_t)a * L_ + bb];
            unsigned u = __float_as_uint(sv);
            u = (u & 0x80000000u) ? ~u : (u | 0x80000000u);
            int i = a < bb ? a : bb, j = a < bb ? bb : a;
            unsigned long long key =
                ((unsigned long long)u << 18) |
                (unsigned long long)(0x3FFFFu - (((unsigned)i << 9) | (unsigned)j));
            if (key > mk) mk = key;
          }
        }
#pragma unroll
        for (int off = 32; off; off >>= 1) {
          unsigned long long o = __shfl_xor(mk, off);
          if (o > mk) mk = o;
        }
        if (lane == 0) {
          bestkey[a] = mk;
          needs[a] = 0;
        }
      }
      __syncthreads();
    }
    // B: mutual-best match
    for (int idx = tid; idx < nLive; idx += 512) {
      int a = cur[idx];
      unsigned pk = 0x3FFFFu - (unsigned)(bestkey[a] & 0x3FFFFull);
      int i = (int)(pk >> 9), j = (int)(pk & 511u);
      int p = (i == a) ? j : i;
      unsigned pk2 = 0x3FFFFu - (unsigned)(bestkey[p] & 0x3FFFFull);
      int i2 = (int)(pk2 >> 9), j2 = (int)(pk2 & 511u);
      int p2 = (i2 == p) ? j2 : i2;
      if (p2 == a) {
        partner[a] = (short)p;
        liveF[a] = 0;
      }
    }
    __syncthreads();
    // C: compact live list into nxt + mark tokens whose best died
    for (int idx = tid; idx < nLive; idx += 512) {
      int a = cur[idx];
      if (liveF[a]) {
        unsigned pk = 0x3FFFFu - (unsigned)(bestkey[a] & 0x3FFFFull);
        int i = (int)(pk >> 9), j = (int)(pk & 511u);
        int p = (i == a) ? j : i;
        if (!liveF[p]) needs[a] = 1;
        int pos = atomicAdd(&cnt[par ^ 1], 1);
        nxt[pos] = (short)a;
      }
    }
    __syncthreads();
  }
  // keep list: kept token = smaller index of each pair, ascending order
  if (wave == 0) {
    int base = 0;
    for (int c = 0; c < 8; ++c) {
      int a = c * 64 + lane;
      bool kept = partner[a] > a;
      unsigned long long m = __ballot(kept);
      int pos = base + (int)__popcll(m & ((1ull << lane) - 1ull));
      if (kept) {
        keepI[b * K_ + pos] = a;
        keepJ[b * K_ + pos] = partner[a];
      }
      base += (int)__popcll(m);
    }
  }
}

// ------- Kernel 5: fused merge; 4096 blocks (2 per output row) -------
__global__ __launch_bounds__(256) void merge_kernel(const float* __restrict__ x,
                                                    const float* __restrict__ s,
                                                    const float* __restrict__ gn,
                                                    const int* __restrict__ keepI,
                                                    const int* __restrict__ keepJ,
                                                    float* __restrict__ xm,
                                                    float* __restrict__ sm) {
  int blk = blockIdx.x;  // 4096
  int row = blk >> 1, half = blk & 1;
  int b = row >> 8;
  int i = keepI[row], j = keepJ[row];
  int t = threadIdx.x;
  if (half == 0) {
    float wi = gn[(size_t)b * L_ + i], wj = gn[(size_t)b * L_ + j];
    float tot = wi + wj + 1e-8f;
    const float4* xi = (const float4*)(x + ((size_t)b * L_ + i) * D_);
    const float4* xj = (const float4*)(x + ((size_t)b * L_ + j) * D_);
    float4* o = (float4*)(xm + (size_t)row * D_);
    float4 a = xi[t], c = xj[t];
    float4 r;
    r.x = (wi * a.x + wj * c.x) / tot;
    r.y = (wi * a.y + wj * c.y) / tot;
    r.z = (wi * a.z + wj * c.z) / tot;
    r.w = (wi * a.w + wj * c.w) / tot;
    o[t] = r;
  }
  {
    size_t off = (size_t)half * (N_ / 2);
    const float4* si = (const float4*)(s + ((size_t)b * L_ + i) * N_ + off);
    const float4* sj = (const float4*)(s + ((size_t)b * L_ + j) * N_ + off);
    float4* o = (float4*)(sm + (size_t)row * N_ + off);
    for (int tt = t; tt < N_ / 8; tt += 256) {
      float4 a = si[tt], c = sj[tt];
      float4 r;
      r.x = a.x + c.x;
      r.y = a.y + c.y;
      r.z = a.z + c.z;
      r.w = a.w + c.w;
      o[tt] = r;
    }
  }
}

extern "C" void kernel_launch(void* const* d_in, const int* in_sizes, int n_in,
                              void* d_out, int out_size, void* d_ws, size_t ws_size,
                              hipStream_t stream) {
  (void)in_sizes; (void)n_in; (void)out_size; (void)ws_size;
  const float* x = (const float*)d_in[0];
  const float* src = (const float*)d_in[1];
  const float* W = (const float*)d_in[2];

  float* ws = (float*)d_ws;
  float* Wt = ws;                                   // 65536
  float* gu = Wt + 65536;                           // 262144
  float* gn = gu + (size_t)B_ * L_ * GD_;           // 4096
  float* sim = gn + (size_t)B_ * L_;                // 2097152
  int* keepI = (int*)(sim + (size_t)B_ * L_ * L_);  // 2048
  int* keepJ = keepI + B_ * K_;                     // 2048
  unsigned long long* cand = (unsigned long long*)(keepJ + B_ * K_);  // 8*512*16 u64

  float* xm = (float*)d_out;
  float* sm = xm + (size_t)B_ * K_ * D_;

  wt_kernel<<<256, 256, 0, stream>>>(W, Wt);
  gproj_kernel<<<256, 256, 0, stream>>>(x, Wt, gu, gn);
  sim_kernel<<<dim3(16, 16, 8), 256, 0, stream>>>(gu, sim);
  topk_kernel<<<1024, 256, 0, stream>>>(sim, cand);
  match_kernel<<<B_, 512, 0, stream>>>(sim, cand, keepI, keepJ);
  merge_kernel<<<B_ * K_ * 2, 256, 0, stream>>>(x, src, gn, keepI, keepJ, xm, sm);
}